// Round 16
// baseline (778.490 us; speedup 1.0000x reference)
//
#include <hip/hip_runtime.h>

// ---------------------------------------------------------------------------
// Transformer_16784732193201 — round 16
// vs r15/r11: LayerNorm FOLDED into consumer GEMM weights.
//   LN(x) consumed as: s*(W'·x) - (mu*s)*c1[n] + cb[n], W'=W*sa (bf16),
//   c1=rowsum(W'), cb=W·sb+bias — precomputed on device.
//   Producers (gemm8r) write xres + per-row {s, mu*s} stats (663KB) instead
//   of a 42.5MB lnout buffer. BatchNorm folds fully into conv weights.
// Saves ~250MB of HBM writes and shortens the gemm8r serial epilogue.
// ws layout:
//   xres  bf16 [82944,256]               @ 0
//   bufA  bf16 [82944,256]               @ 84934656
//   bufB  bf16 [82944,768]               @ 127401984
//   packed weights + consts + stats      @ 254803968
// ---------------------------------------------------------------------------

typedef __attribute__((ext_vector_type(2))) float f32x2;
typedef __attribute__((ext_vector_type(4))) float f32x4;
typedef __attribute__((ext_vector_type(8))) short s16x8;
typedef __attribute__((ext_vector_type(4))) unsigned short u16x4;
typedef __attribute__((ext_vector_type(8))) unsigned short u16x8;

__device__ __forceinline__ float bf2f(unsigned short u) {
  unsigned int v = ((unsigned int)u) << 16;
  return __builtin_bit_cast(float, v);
}
__device__ __forceinline__ unsigned short f2bf(float f) {
  unsigned int u = __builtin_bit_cast(unsigned int, f);
  u += 0x7fffu + ((u >> 16) & 1u);
  return (unsigned short)(u >> 16);
}

#define GLD16(gp, lp)                                                       \
  __builtin_amdgcn_global_load_lds(                                         \
      (const __attribute__((address_space(1))) void*)(gp),                  \
      (__attribute__((address_space(3))) void*)(lp), 16, 0, 0)

// ---------------------------------------------------------------------------
// gemm8s: 8-wave GEMM consuming UN-normalized xres with folded LN.
// out = s*(W'·x) - ms*c1[col] + cb[col]  (EPI 1: relu). K=256 fixed.
// ---------------------------------------------------------------------------
template <int EPI, int NY>
__global__ __launch_bounds__(512) void gemm8s(
    const unsigned short* __restrict__ A, const unsigned short* __restrict__ W,
    const f32x2* __restrict__ stats, const float* __restrict__ c1,
    const float* __restrict__ cb, unsigned short* __restrict__ Cout, int ldc) {
  __shared__ unsigned short Alds[128 * 64];
  __shared__ unsigned short Blds[256 * 64];
  __shared__ f32x2 sLDS[128];
  const int tid = threadIdx.x, wave = tid >> 6, lane = tid & 63;
  const int nwg = gridDim.x;
  const int swz = (blockIdx.x & 7) * (nwg >> 3) + (blockIdx.x >> 3);
  const int row0 = (swz / NY) * 128, ncol0 = (swz % NY) * 256;
  const int wr = wave >> 2, wc = wave & 3;
  const int fr = lane & 15, g4 = lane >> 4, ko = g4 * 8;
  const int swr = (fr & 7) << 3;
  const int l8 = lane >> 3;
  const int lkS = ((lane & 7) ^ l8) * 8;

  if (tid < 128) sLDS[tid] = stats[row0 + tid];

  f32x4 acc[4][4];
#pragma unroll
  for (int i = 0; i < 4; ++i)
#pragma unroll
    for (int j = 0; j < 4; ++j) acc[i][j] = (f32x4)0.f;

  for (int kt = 0; kt < 4; ++kt) {
    __syncthreads();
#pragma unroll
    for (int j = 0; j < 2; ++j) {
      int ci = wave * 2 + j;
      const unsigned short* src = A + (size_t)(row0 + ci * 8 + l8) * 256 + kt * 64 + lkS;
      GLD16(src, &Alds[ci * 512]);
    }
#pragma unroll
    for (int j = 0; j < 4; ++j) {
      int ci = wave * 4 + j;
      const unsigned short* src = W + (size_t)(ncol0 + ci * 8 + l8) * 256 + kt * 64 + lkS;
      GLD16(src, &Blds[ci * 512]);
    }
    __syncthreads();
#pragma unroll
    for (int kk = 0; kk < 2; ++kk) {
      s16x8 af[4], bfr[4];
#pragma unroll
      for (int i = 0; i < 4; ++i)
        af[i] = *(const s16x8*)&Alds[(wr * 64 + i * 16 + fr) * 64 + ((kk * 32 + ko) ^ swr)];
#pragma unroll
      for (int j = 0; j < 4; ++j)
        bfr[j] = *(const s16x8*)&Blds[(wc * 64 + j * 16 + fr) * 64 + ((kk * 32 + ko) ^ swr)];
#pragma unroll
      for (int i = 0; i < 4; ++i)
#pragma unroll
        for (int j = 0; j < 4; ++j)
          acc[i][j] =
              __builtin_amdgcn_mfma_f32_16x16x32_bf16(af[i], bfr[j], acc[i][j], 0, 0, 0);
    }
  }

  const int cr = g4 * 4;
#pragma unroll
  for (int i = 0; i < 4; ++i) {
#pragma unroll
    for (int j = 0; j < 4; ++j) {
      int col = ncol0 + wc * 64 + j * 16 + fr;
      float c1v = c1[col], cbv = cb[col];
#pragma unroll
      for (int r = 0; r < 4; ++r) {
        int rl = wr * 64 + i * 16 + cr + r;
        f32x2 st = sLDS[rl];
        float v = st[0] * acc[i][j][r] - st[1] * c1v + cbv;
        if constexpr (EPI == 1) v = fmaxf(v, 0.f);
        Cout[(size_t)(row0 + rl) * ldc + col] = f2bf(v);
      }
    }
  }
}

// ---------------------------------------------------------------------------
// gemm8r: GEMM + bias + bf16 residual -> xres, plus per-row LN stats.
// BM=128, BN=256=N, NY=1. MODE 0: writes stats {s, mu*s}; MODE 1: no stats.
// LDS-bounced coalesced epilogue (r11 structure, no lnout pass).
// ---------------------------------------------------------------------------
template <int MODE>
__global__ __launch_bounds__(512) void gemm8r(
    const unsigned short* __restrict__ A, const unsigned short* __restrict__ W,
    const float* __restrict__ bias, unsigned short* __restrict__ xres,
    f32x2* __restrict__ stats, int K) {
  constexpr int ES = 264;                  // padded row stride (shorts)
  __shared__ unsigned short SM[128 * ES];  // union: K-loop A|B tiles / E
  __shared__ float redS[128][4];
  __shared__ float redQ[128][4];
  unsigned short* Alds = SM;
  unsigned short* Blds = SM + 128 * 64;

  const int tid = threadIdx.x, wave = tid >> 6, lane = tid & 63;
  const int nwg = gridDim.x;
  const int swz = (blockIdx.x & 7) * (nwg >> 3) + (blockIdx.x >> 3);
  const int row0 = swz * 128;
  const int wr = wave >> 2, wc = wave & 3;
  const int fr = lane & 15, g4 = lane >> 4, ko = g4 * 8;
  const int swr = (fr & 7) << 3;
  const int l8 = lane >> 3;
  const int lkS = ((lane & 7) ^ l8) * 8;

  f32x4 acc[4][4];
#pragma unroll
  for (int i = 0; i < 4; ++i)
#pragma unroll
    for (int j = 0; j < 4; ++j) acc[i][j] = (f32x4)0.f;

  const int nkt = K / 64;
  for (int kt = 0; kt < nkt; ++kt) {
    __syncthreads();
#pragma unroll
    for (int j = 0; j < 2; ++j) {
      int ci = wave * 2 + j;
      const unsigned short* src = A + (size_t)(row0 + ci * 8 + l8) * K + kt * 64 + lkS;
      GLD16(src, &Alds[ci * 512]);
    }
#pragma unroll
    for (int j = 0; j < 4; ++j) {
      int ci = wave * 4 + j;
      const unsigned short* src = W + (size_t)(ci * 8 + l8) * K + kt * 64 + lkS;
      GLD16(src, &Blds[ci * 512]);
    }
    __syncthreads();
#pragma unroll
    for (int kk = 0; kk < 2; ++kk) {
      s16x8 af[4], bfr[4];
#pragma unroll
      for (int i = 0; i < 4; ++i)
        af[i] = *(const s16x8*)&Alds[(wr * 64 + i * 16 + fr) * 64 + ((kk * 32 + ko) ^ swr)];
#pragma unroll
      for (int j = 0; j < 4; ++j)
        bfr[j] = *(const s16x8*)&Blds[(wc * 64 + j * 16 + fr) * 64 + ((kk * 32 + ko) ^ swr)];
#pragma unroll
      for (int i = 0; i < 4; ++i)
#pragma unroll
        for (int j = 0; j < 4; ++j)
          acc[i][j] =
              __builtin_amdgcn_mfma_f32_16x16x32_bf16(af[i], bfr[j], acc[i][j], 0, 0, 0);
    }
  }

  const int cr = g4 * 4;
  float bv[4];
#pragma unroll
  for (int j = 0; j < 4; ++j) bv[j] = bias[wc * 64 + j * 16 + fr];

  const int erow = tid >> 5;       // 0..15
  const int ec8 = (tid & 31) * 8;  // fixed 16B col chunk

  __syncthreads();  // all K-loop LDS reads done; SM reusable as E
  // (1) coalesced xres -> E
#pragma unroll
  for (int p = 0; p < 8; ++p) {
    int row = p * 16 + erow;
    *(u16x8*)&SM[row * ES + ec8] =
        *(const u16x8*)&xres[(size_t)(row0 + row) * 256 + ec8];
  }
  __syncthreads();
  // (2) fragment add + stats in fp32; v back to E as bf16
#pragma unroll
  for (int i = 0; i < 4; ++i) {
    float s4[4] = {0.f, 0.f, 0.f, 0.f};
    float q4[4] = {0.f, 0.f, 0.f, 0.f};
#pragma unroll
    for (int j = 0; j < 4; ++j) {
      int col = wc * 64 + j * 16 + fr;
#pragma unroll
      for (int r = 0; r < 4; ++r) {
        int rl = wr * 64 + i * 16 + cr + r;
        float v = acc[i][j][r] + bv[j] + bf2f(SM[rl * ES + col]);
        SM[rl * ES + col] = f2bf(v);
        s4[r] += v;
        q4[r] += v * v;
      }
    }
    if constexpr (MODE == 0) {
#pragma unroll
      for (int r = 0; r < 4; ++r) {
        float s = s4[r], q = q4[r];
#pragma unroll
        for (int off = 1; off <= 8; off <<= 1) {
          s += __shfl_xor(s, off);
          q += __shfl_xor(q, off);
        }
        if (fr == 0) {
          int rl = wr * 64 + i * 16 + cr + r;
          redS[rl][wc] = s;
          redQ[rl][wc] = q;
        }
      }
    }
  }
  __syncthreads();
  // (3) coalesced writeback + per-row stats
#pragma unroll
  for (int p = 0; p < 8; ++p) {
    int row = p * 16 + erow;
    u16x8 vb = *(const u16x8*)&SM[row * ES + ec8];
    *(u16x8*)&xres[(size_t)(row0 + row) * 256 + ec8] = vb;
    if constexpr (MODE == 0) {
      if (ec8 == 0) {
        float s = redS[row][0] + redS[row][1] + redS[row][2] + redS[row][3];
        float q = redQ[row][0] + redQ[row][1] + redQ[row][2] + redQ[row][3];
        float mean = s * (1.f / 256.f);
        float var = fmaxf(q - 256.f * mean * mean, 0.f) * (1.f / 255.f);
        float scl = 1.f / (sqrtf(var) + 1e-6f);
        f32x2 st;
        st[0] = scl;
        st[1] = mean * scl;
        stats[row0 + row] = st;
      }
    }
  }
}

// ---------------------------------------------------------------------------
// Final 51-col conv (BN folded into weights): out = cw'·x + ccb. A = xres.
// ---------------------------------------------------------------------------
__global__ __launch_bounds__(256) void gemm_cv(
    const unsigned short* __restrict__ A, const unsigned short* __restrict__ W,
    const float* __restrict__ bias, float* __restrict__ out) {
  constexpr int BM = 128, BK = 64, BN = 64, WN = 32, FN = 2;
  __shared__ unsigned short Alds[BM * BK];
  __shared__ unsigned short Blds[BN * BK];
  const int tid = threadIdx.x, wave = tid >> 6, lane = tid & 63;
  const int nwg = gridDim.x;
  const int swz = (blockIdx.x & 7) * (nwg >> 3) + (blockIdx.x >> 3);
  const int row0 = swz * BM;
  const int wr = wave >> 1, wc = wave & 1;
  const int fr = lane & 15, g4 = lane >> 4, ko = g4 * 8;
  const int swr = (fr & 7) << 3;
  const int l8 = lane >> 3;
  const int lkS = ((lane & 7) ^ l8) * 8;

  f32x4 acc[4][FN];
#pragma unroll
  for (int i = 0; i < 4; ++i)
#pragma unroll
    for (int j = 0; j < FN; ++j) acc[i][j] = (f32x4)0.f;

  for (int kt = 0; kt < 4; ++kt) {
    __syncthreads();
#pragma unroll
    for (int j = 0; j < 4; ++j) {
      int ci = wave * 4 + j;
      const unsigned short* src = A + (size_t)(row0 + ci * 8 + l8) * 256 + kt * BK + lkS;
      GLD16(src, &Alds[ci * 512]);
    }
    {
      int ci = wave * 2;
      int brow = ci * 8 + l8;
      if (brow > 50) brow = 50;
      const unsigned short* src = W + (size_t)brow * 256 + kt * BK + lkS;
      GLD16(src, &Blds[ci * 512]);
      int brow2 = (ci + 1) * 8 + l8;
      if (brow2 > 50) brow2 = 50;
      const unsigned short* src2 = W + (size_t)brow2 * 256 + kt * BK + lkS;
      GLD16(src2, &Blds[(ci + 1) * 512]);
    }
    __syncthreads();
#pragma unroll
    for (int kk = 0; kk < 2; ++kk) {
      s16x8 af[4], bfr[FN];
#pragma unroll
      for (int i = 0; i < 4; ++i)
        af[i] = *(const s16x8*)&Alds[(wr * 64 + i * 16 + fr) * BK + ((kk * 32 + ko) ^ swr)];
#pragma unroll
      for (int j = 0; j < FN; ++j)
        bfr[j] = *(const s16x8*)&Blds[(wc * WN + j * 16 + fr) * BK + ((kk * 32 + ko) ^ swr)];
#pragma unroll
      for (int i = 0; i < 4; ++i)
#pragma unroll
        for (int j = 0; j < FN; ++j)
          acc[i][j] =
              __builtin_amdgcn_mfma_f32_16x16x32_bf16(af[i], bfr[j], acc[i][j], 0, 0, 0);
    }
  }

  const int cr = g4 * 4;
#pragma unroll
  for (int i = 0; i < 4; ++i) {
#pragma unroll
    for (int j = 0; j < FN; ++j) {
      int col = wc * WN + j * 16 + fr;
      if (col >= 51) continue;
      float bv = bias[col];
#pragma unroll
      for (int r = 0; r < 4; ++r) {
        int row = row0 + wr * 64 + i * 16 + cr + r;
        out[(size_t)row * 51 + col] = acc[i][j][r] + bv;
      }
    }
  }
}

// ---------------------------------------------------------------------------
// addpos_s: x+pos -> xres (bf16) + per-row LN stats. 1 wave per row.
// ---------------------------------------------------------------------------
__global__ __launch_bounds__(256) void addpos_s(const f32x4* __restrict__ x,
                                                const f32x4* __restrict__ pos,
                                                unsigned short* __restrict__ xres,
                                                f32x2* __restrict__ stats) {
  const int wave = threadIdx.x >> 6, lane = threadIdx.x & 63;
  const size_t row = (size_t)blockIdx.x * 4 + wave;
  f32x4 v = x[row * 64 + lane] + pos[(row % 81) * 64 + lane];
  u16x4 xb;
#pragma unroll
  for (int j = 0; j < 4; ++j) xb[j] = f2bf(v[j]);
  *(u16x4*)(xres + row * 256 + lane * 4) = xb;
  float s = v[0] + v[1] + v[2] + v[3];
#pragma unroll
  for (int off = 32; off >= 1; off >>= 1) s += __shfl_xor(s, off);
  float mean = s * (1.f / 256.f);
  f32x4 d = v - mean;
  float sq = d[0] * d[0] + d[1] * d[1] + d[2] * d[2] + d[3] * d[3];
#pragma unroll
  for (int off = 32; off >= 1; off >>= 1) sq += __shfl_xor(sq, off);
  float var = sq * (1.f / 255.f);
  float scl = 1.f / (sqrtf(var) + 1e-6f);
  if (lane == 0) {
    f32x2 st;
    st[0] = scl;
    st[1] = mean * scl;
    stats[row] = st;
  }
}

// ---------------------------------------------------------------------------
// MFMA strided sparse attention (unchanged).
// ---------------------------------------------------------------------------
__global__ __launch_bounds__(256) void attn_mfma(const unsigned short* __restrict__ qkv,
                                                 unsigned short* __restrict__ o) {
  constexpr int LS = 40;
  const int wave = threadIdx.x >> 6, lane = threadIdx.x & 63;
  const int sid = blockIdx.x * 4 + wave;
  const int m = sid % 3, hh = (sid / 3) & 7, b = sid / 24;
  __shared__ unsigned short VtS[4][32 * LS];
  __shared__ unsigned short PlS[4][32 * LS];
  unsigned short* vt = VtS[wave];
  unsigned short* pl = PlS[wave];

  const unsigned short* base = qkv + (size_t)b * 81 * 768 + (size_t)m * 768 + hh * 32;
  const int fr = lane & 15;
  const int ko = (lane >> 4) * 8;
  const int g4 = lane >> 4;

  s16x8 qf[2], kf[2];
#pragma unroll
  for (int i = 0; i < 2; ++i) {
    int g = fr + 16 * i;
    if (g > 26) g = 26;
    const unsigned short* qp = base + (size_t)g * 2304 + ko;
    qf[i] = *(const s16x8*)qp;
    kf[i] = *(const s16x8*)(qp + 256);
  }

#pragma unroll
  for (int it = 0; it < 2; ++it) {
    int slot = it * 64 + lane;
    int g = slot >> 2, s = slot & 3;
    if (g < 27) {
      u16x8 v = *(const u16x8*)(base + (size_t)g * 2304 + 512 + s * 8);
#pragma unroll
      for (int j = 0; j < 8; ++j) vt[(s * 8 + j) * LS + g] = v[j];
    } else {
#pragma unroll
      for (int j = 0; j < 8; ++j) vt[(s * 8 + j) * LS + g] = 0;
    }
  }

  f32x4 sacc[2][2];
#pragma unroll
  for (int i = 0; i < 2; ++i)
#pragma unroll
    for (int j = 0; j < 2; ++j) sacc[i][j] = (f32x4)0.f;
#pragma unroll
  for (int i = 0; i < 2; ++i)
#pragma unroll
    for (int j = 0; j < 2; ++j)
      sacc[i][j] = __builtin_amdgcn_mfma_f32_16x16x32_bf16(qf[i], kf[j], sacc[i][j], 0, 0, 0);

  const float scale = 0.17677669529663687f;
  const bool v1 = fr < 11;
#pragma unroll
  for (int i = 0; i < 2; ++i) {
#pragma unroll
    for (int r = 0; r < 4; ++r) {
      float a0 = sacc[i][0][r] * scale;
      float a1 = v1 ? sacc[i][1][r] * scale : -3.0e38f;
      float mx = fmaxf(a0, a1);
#pragma unroll
      for (int off = 1; off <= 8; off <<= 1) mx = fmaxf(mx, __shfl_xor(mx, off));
      float e0 = __expf(a0 - mx);
      float e1 = v1 ? __expf(a1 - mx) : 0.f;
      float sm = e0 + e1;
#pragma unroll
      for (int off = 1; off <= 8; off <<= 1) sm += __shfl_xor(sm, off);
      float inv = 1.f / sm;
      int row = i * 16 + 4 * g4 + r;
      pl[row * LS + fr] = f2bf(e0 * inv);
      pl[row * LS + 16 + fr] = f2bf(e1 * inv);
    }
  }
  __syncthreads();

  s16x8 pf[2], vf[2];
#pragma unroll
  for (int i = 0; i < 2; ++i) pf[i] = *(const s16x8*)&pl[(fr + 16 * i) * LS + ko];
#pragma unroll
  for (int j = 0; j < 2; ++j) vf[j] = *(const s16x8*)&vt[(fr + 16 * j) * LS + ko];

  f32x4 oacc[2][2];
#pragma unroll
  for (int i = 0; i < 2; ++i)
#pragma unroll
    for (int j = 0; j < 2; ++j) oacc[i][j] = (f32x4)0.f;
#pragma unroll
  for (int i = 0; i < 2; ++i)
#pragma unroll
    for (int j = 0; j < 2; ++j)
      oacc[i][j] = __builtin_amdgcn_mfma_f32_16x16x32_bf16(pf[i], vf[j], oacc[i][j], 0, 0, 0);

  __syncthreads();
#pragma unroll
  for (int i = 0; i < 2; ++i)
#pragma unroll
    for (int j = 0; j < 2; ++j)
#pragma unroll
      for (int r = 0; r < 4; ++r)
        vt[(i * 16 + 4 * g4 + r) * LS + j * 16 + fr] = f2bf(oacc[i][j][r]);
  __syncthreads();

#pragma unroll
  for (int it = 0; it < 2; ++it) {
    int slot = it * 64 + lane;
    int g = slot >> 2, s = slot & 3;
    if (g < 27) {
      u16x8 v = *(const u16x8*)&vt[g * LS + s * 8];
      *(u16x8*)(o + (size_t)(b * 81 + m + 3 * g) * 256 + hh * 32 + s * 8) = v;
    }
  }
}

// ---------------------------------------------------------------------------
// Weight packing / constant kernels
// ---------------------------------------------------------------------------
__global__ __launch_bounds__(256) void cvt_kernel(const f32x4* __restrict__ src,
                                                  u16x4* __restrict__ dst, int n4) {
  int i = blockIdx.x * 256 + threadIdx.x;
  if (i < n4) {
    f32x4 v = src[i];
    u16x4 o;
#pragma unroll
    for (int j = 0; j < 4; ++j) o[j] = f2bf(v[j]);
    dst[i] = o;
  }
}

// pack Wq|Wk|Wv scaled by ln1_a -> wqkv3 bf16 [3][768][256]
__global__ __launch_bounds__(256) void qkvpack_kernel(const float* __restrict__ Wq,
                                                      const float* __restrict__ Wk,
                                                      const float* __restrict__ Wv,
                                                      const float* __restrict__ ln1_a,
                                                      u16x4* __restrict__ dst) {
  int i4 = blockIdx.x * 256 + threadIdx.x;  // 147456
  int e = i4 * 4;
  int l = e / 196608;
  int r = (e / 256) % 768;
  int c = e & 255;
  const float* src;
  if (r < 256) src = Wq + (size_t)l * 65536 + r * 256 + c;
  else if (r < 512) src = Wk + (size_t)l * 65536 + (r - 256) * 256 + c;
  else src = Wv + (size_t)l * 65536 + (r - 512) * 256 + c;
  f32x4 v = *(const f32x4*)src;
  f32x4 sa = *(const f32x4*)(ln1_a + l * 256 + c);
  u16x4 o;
#pragma unroll
  for (int j = 0; j < 4; ++j) o[j] = f2bf(v[j] * sa[j]);
  dst[i4] = o;
}

// per-col consts for QKV: c1 = rowsum(bf16(W*sa)), cb = W·sb + bias
__global__ __launch_bounds__(256) void qkvconst_kernel(
    const float* __restrict__ Wq, const float* __restrict__ Wk,
    const float* __restrict__ Wv, const float* __restrict__ ln1_a,
    const float* __restrict__ ln1_b, const float* __restrict__ bq,
    const float* __restrict__ bk, const float* __restrict__ bv,
    float* __restrict__ c1, float* __restrict__ cb) {
  int w = blockIdx.x * 4 + (threadIdx.x >> 6);  // 2304 waves
  int lane = threadIdx.x & 63;
  int l = w / 768, n = w % 768;
  const float* src;
  float bias;
  if (n < 256) { src = Wq + (size_t)l * 65536 + n * 256; bias = bq[l * 256 + n]; }
  else if (n < 512) { src = Wk + (size_t)l * 65536 + (n - 256) * 256; bias = bk[l * 256 + n - 256]; }
  else { src = Wv + (size_t)l * 65536 + (n - 512) * 256; bias = bv[l * 256 + n - 512]; }
  float s1 = 0.f, s2 = 0.f;
#pragma unroll
  for (int j = 0; j < 4; ++j) {
    int k = lane * 4 + j;
    float wv = src[k];
    s1 += bf2f(f2bf(wv * ln1_a[l * 256 + k]));
    s2 += wv * ln1_b[l * 256 + k];
  }
#pragma unroll
  for (int off = 32; off >= 1; off >>= 1) {
    s1 += __shfl_xor(s1, off);
    s2 += __shfl_xor(s2, off);
  }
  if (lane == 0) {
    c1[w] = s1;
    cb[w] = s2 + bias;
  }
}

// pack W1 scaled by ln2_a -> bf16 [3][512][256]
__global__ __launch_bounds__(256) void w1pack_kernel(const float* __restrict__ W1,
                                                     const float* __restrict__ ln2_a,
                                                     u16x4* __restrict__ dst) {
  int i4 = blockIdx.x * 256 + threadIdx.x;  // 98304
  int e = i4 * 4;
  int l = e / 131072;
  int c = e & 255;
  f32x4 v = *(const f32x4*)(W1 + e);
  f32x4 sa = *(const f32x4*)(ln2_a + l * 256 + c);
  u16x4 o;
#pragma unroll
  for (int j = 0; j < 4; ++j) o[j] = f2bf(v[j] * sa[j]);
  dst[i4] = o;
}

__global__ __launch_bounds__(256) void w1const_kernel(
    const float* __restrict__ W1, const float* __restrict__ ln2_a,
    const float* __restrict__ ln2_b, const float* __restrict__ b1,
    float* __restrict__ c1, float* __restrict__ cb) {
  int w = blockIdx.x * 4 + (threadIdx.x >> 6);  // 1536 waves
  int lane = threadIdx.x & 63;
  int l = w / 512, n = w % 512;
  const float* src = W1 + (size_t)l * 131072 + n * 256;
  float s1 = 0.f, s2 = 0.f;
#pragma unroll
  for (int j = 0; j < 4; ++j) {
    int k = lane * 4 + j;
    float wv = src[k];
    s1 += bf2f(f2bf(wv * ln2_a[l * 256 + k]));
    s2 += wv * ln2_b[l * 256 + k];
  }
#pragma unroll
  for (int off = 32; off >= 1; off >>= 1) {
    s1 += __shfl_xor(s1, off);
    s2 += __shfl_xor(s2, off);
  }
  if (lane == 0) {
    c1[w] = s1;
    cb[w] = s2 + b1[l * 512 + n];
  }
}

// pack conv_w * bn_g * 1/sqrt(1+eps) -> bf16 [51][256]
__global__ __launch_bounds__(256) void cwpack_kernel(const float* __restrict__ cw,
                                                     const float* __restrict__ bn_g,
                                                     u16x4* __restrict__ dst) {
  int i4 = blockIdx.x * 256 + threadIdx.x;
  if (i4 >= 3264) return;
  int e = i4 * 4;
  int c = e & 255;
  const float is = 0.9999950000374997f;
  f32x4 v = *(const f32x4*)(cw + e);
  f32x4 g = *(const f32x4*)(bn_g + c);
  u16x4 o;
#pragma unroll
  for (int j = 0; j < 4; ++j) o[j] = f2bf(v[j] * g[j] * is);
  dst[i4] = o;
}

__global__ __launch_bounds__(256) void cvconst_kernel(const float* __restrict__ cw,
                                                      const float* __restrict__ bn_b,
                                                      const float* __restrict__ conv_b,
                                                      float* __restrict__ ccb) {
  int w = blockIdx.x * 4 + (threadIdx.x >> 6);
  if (w >= 51) return;
  int lane = threadIdx.x & 63;
  const float* src = cw + (size_t)w * 256;
  float s = 0.f;
#pragma unroll
  for (int j = 0; j < 4; ++j) {
    int k = lane * 4 + j;
    s += src[k] * bn_b[k];
  }
#pragma unroll
  for (int off = 32; off >= 1; off >>= 1) s += __shfl_xor(s, off);
  if (lane == 0) ccb[w] = s + conv_b[w];
}

extern "C" void kernel_launch(void* const* d_in, const int* in_sizes, int n_in,
                              void* d_out, int out_size, void* d_ws, size_t ws_size,
                              hipStream_t stream) {
  const float* x      = (const float*)d_in[0];
  const float* pos    = (const float*)d_in[1];
  const float* ln1_a  = (const float*)d_in[2];
  const float* ln1_b  = (const float*)d_in[3];
  const float* Wq     = (const float*)d_in[4];
  const float* bq     = (const float*)d_in[5];
  const float* Wk     = (const float*)d_in[6];
  const float* bk     = (const float*)d_in[7];
  const float* Wv     = (const float*)d_in[8];
  const float* bv     = (const float*)d_in[9];
  const float* Wo     = (const float*)d_in[10];
  const float* bo     = (const float*)d_in[11];
  const float* ln2_a  = (const float*)d_in[12];
  const float* ln2_b  = (const float*)d_in[13];
  const float* W1     = (const float*)d_in[14];
  const float* b1     = (const float*)d_in[15];
  const float* W2     = (const float*)d_in[16];
  const float* b2     = (const float*)d_in[17];
  const float* bn_g   = (const float*)d_in[18];
  const float* bn_b   = (const float*)d_in[19];
  const float* conv_w = (const float*)d_in[20];
  const float* conv_b = (const float*)d_in[21];

  char* ws = (char*)d_ws;
  unsigned short* xres = (unsigned short*)ws;  // bf16 residual stream
  unsigned short* bufA = (unsigned short*)(ws + 84934656);
  unsigned short* bufB = (unsigned short*)(ws + 127401984);
  unsigned short* wqkv3 = (unsigned short*)(ws + 254803968);
  unsigned short* wo3 = wqkv3 + 589824;
  unsigned short* w13 = wo3 + 196608;
  unsigned short* w23 = w13 + 393216;
  unsigned short* cw  = w23 + 393216;   // 13056 shorts, pad to 13312
  float* fbase = (float*)(ws + 254803968 + 3171840);
  float* qc1 = fbase;          // [3][768]
  float* qcb = fbase + 2304;   // [3][768]
  float* fc1 = fbase + 4608;   // [3][512]
  float* fcb = fbase + 6144;   // [3][512]
  float* ccb = fbase + 7680;   // [51] pad 256
  f32x2* stats = (f32x2*)(fbase + 7936);  // [82944] f32x2

  auto cvt = [&](const float* s, unsigned short* d, int n) {
    int n4 = n / 4;
    cvt_kernel<<<(n4 + 255) / 256, 256, 0, stream>>>((const f32x4*)s, (u16x4*)d, n4);
  };
  qkvpack_kernel<<<576, 256, 0, stream>>>(Wq, Wk, Wv, ln1_a, (u16x4*)wqkv3);
  qkvconst_kernel<<<576, 256, 0, stream>>>(Wq, Wk, Wv, ln1_a, ln1_b, bq, bk, bv, qc1, qcb);
  w1pack_kernel<<<384, 256, 0, stream>>>(W1, ln2_a, (u16x4*)w13);
  w1const_kernel<<<384, 256, 0, stream>>>(W1, ln2_a, ln2_b, b1, fc1, fcb);
  cwpack_kernel<<<13, 256, 0, stream>>>(conv_w, bn_g, (u16x4*)cw);
  cvconst_kernel<<<13, 256, 0, stream>>>(conv_w, bn_b, conv_b, ccb);
  cvt(Wo, wo3, 196608);
  cvt(W2, w23, 393216);

  // x+pos -> xres + stats
  addpos_s<<<20736, 256, 0, stream>>>((const f32x4*)x, (const f32x4*)pos, xres, stats);

  for (int l = 0; l < 3; ++l) {
    // fused QKV with folded LN1 -> bufB [BT,768]
    gemm8s<0, 3><<<1944, 512, 0, stream>>>(xres, wqkv3 + l * 196608, stats,
                                           qc1 + l * 768, qcb + l * 768, bufB, 768);
    attn_mfma<<<6144, 256, 0, stream>>>(bufB, bufA);
    // O-proj + resid -> xres + stats (for LN2)
    gemm8r<0><<<648, 512, 0, stream>>>(bufA, wo3 + l * 65536, bo + l * 256, xres,
                                       stats, 256);
    // FFN1 (relu) with folded LN2 -> bufB [BT,512]
    gemm8s<1, 2><<<1296, 512, 0, stream>>>(xres, w13 + l * 131072, stats,
                                           fc1 + l * 512, fcb + l * 512, bufB, 512);
    if (l < 2) {
      // FFN2 + resid -> xres + stats (for LN1 of l+1)
      gemm8r<0><<<648, 512, 0, stream>>>(bufB, w23 + l * 131072, b2 + l * 256, xres,
                                         stats, 512);
    } else {
      // FFN2 + resid -> xres (BN folded into conv; no stats)
      gemm8r<1><<<648, 512, 0, stream>>>(bufB, w23 + l * 131072, b2 + l * 256, xres,
                                         stats, 512);
    }
  }
  // final conv with folded BN reads xres -> d_out fp32
  gemm_cv<<<648, 256, 0, stream>>>(xres, cw, ccb, (float*)d_out);
}

// Round 17
// 730.514 us; speedup vs baseline: 1.0657x; 1.0657x over previous
//
#include <hip/hip_runtime.h>

// ---------------------------------------------------------------------------
// Transformer_16784732193201 — round 17 = EXACT restore of round 15 (best,
// 731us). Variants tested and regressed: r12 BM=64 (+3us/disp), r13 T14
// reg-prefetch (+20us/disp, VGPR 92), r14 two-half epilogue (+34us/disp),
// r16 LN-fold-into-weights (+47us total: consumer epilogue cost > producer
// write savings). r11/r15 balance is the measured optimum of this structure.
// ws layout:
//   xres  bf16 [82944,256]               @ 0
//   bufA  bf16 [82944,256]               @ 84934656
//   bufB  bf16 [82944,768]               @ 127401984
//   weights bf16 + fused bias            @ 254803968
// ---------------------------------------------------------------------------

typedef __attribute__((ext_vector_type(4))) float f32x4;
typedef __attribute__((ext_vector_type(8))) short s16x8;
typedef __attribute__((ext_vector_type(4))) unsigned short u16x4;
typedef __attribute__((ext_vector_type(8))) unsigned short u16x8;

__device__ __forceinline__ float bf2f(unsigned short u) {
  unsigned int v = ((unsigned int)u) << 16;
  return __builtin_bit_cast(float, v);
}
__device__ __forceinline__ unsigned short f2bf(float f) {
  unsigned int u = __builtin_bit_cast(unsigned int, f);
  u += 0x7fffu + ((u >> 16) & 1u);
  return (unsigned short)(u >> 16);
}

#define GLD16(gp, lp)                                                       \
  __builtin_amdgcn_global_load_lds(                                         \
      (const __attribute__((address_space(1))) void*)(gp),                  \
      (__attribute__((address_space(3))) void*)(lp), 16, 0, 0)

// ---------------------------------------------------------------------------
// 8-wave GEMM: BM=128, BN=256, 512 threads (2x4 waves), single-buffer 48KB.
// EPI 0: bias -> bf16 ; 1: bias+relu -> bf16.
// ---------------------------------------------------------------------------
template <int EPI, int NY>
__global__ __launch_bounds__(512) void gemm8(
    const unsigned short* __restrict__ A, const unsigned short* __restrict__ W,
    const float* __restrict__ bias, void* __restrict__ Cout, int K, int ldc) {
  __shared__ unsigned short Alds[128 * 64];
  __shared__ unsigned short Blds[256 * 64];
  const int tid = threadIdx.x, wave = tid >> 6, lane = tid & 63;
  const int nwg = gridDim.x;
  const int swz = (blockIdx.x & 7) * (nwg >> 3) + (blockIdx.x >> 3);
  const int row0 = (swz / NY) * 128, ncol0 = (swz % NY) * 256;
  const int wr = wave >> 2, wc = wave & 3;
  const int fr = lane & 15, g4 = lane >> 4, ko = g4 * 8;
  const int swr = (fr & 7) << 3;
  const int l8 = lane >> 3;
  const int lkS = ((lane & 7) ^ l8) * 8;

  f32x4 acc[4][4];
#pragma unroll
  for (int i = 0; i < 4; ++i)
#pragma unroll
    for (int j = 0; j < 4; ++j) acc[i][j] = (f32x4)0.f;

  const int nkt = K / 64;
  for (int kt = 0; kt < nkt; ++kt) {
    __syncthreads();
#pragma unroll
    for (int j = 0; j < 2; ++j) {
      int ci = wave * 2 + j;
      const unsigned short* src = A + (size_t)(row0 + ci * 8 + l8) * K + kt * 64 + lkS;
      GLD16(src, &Alds[ci * 512]);
    }
#pragma unroll
    for (int j = 0; j < 4; ++j) {
      int ci = wave * 4 + j;
      const unsigned short* src = W + (size_t)(ncol0 + ci * 8 + l8) * K + kt * 64 + lkS;
      GLD16(src, &Blds[ci * 512]);
    }
    __syncthreads();
#pragma unroll
    for (int kk = 0; kk < 2; ++kk) {
      s16x8 af[4], bfr[4];
#pragma unroll
      for (int i = 0; i < 4; ++i)
        af[i] = *(const s16x8*)&Alds[(wr * 64 + i * 16 + fr) * 64 + ((kk * 32 + ko) ^ swr)];
#pragma unroll
      for (int j = 0; j < 4; ++j)
        bfr[j] = *(const s16x8*)&Blds[(wc * 64 + j * 16 + fr) * 64 + ((kk * 32 + ko) ^ swr)];
#pragma unroll
      for (int i = 0; i < 4; ++i)
#pragma unroll
        for (int j = 0; j < 4; ++j)
          acc[i][j] =
              __builtin_amdgcn_mfma_f32_16x16x32_bf16(af[i], bfr[j], acc[i][j], 0, 0, 0);
    }
  }

  const int cr = g4 * 4;
#pragma unroll
  for (int i = 0; i < 4; ++i) {
#pragma unroll
    for (int j = 0; j < 4; ++j) {
      int col = ncol0 + wc * 64 + j * 16 + fr;
      float bv = bias[col];
#pragma unroll
      for (int r = 0; r < 4; ++r) {
        int row = row0 + wr * 64 + i * 16 + cr + r;
        float v = acc[i][j][r] + bv;
        if constexpr (EPI == 1) v = fmaxf(v, 0.f);
        ((unsigned short*)Cout)[(size_t)row * ldc + col] = f2bf(v);
      }
    }
  }
}

// ---------------------------------------------------------------------------
// Full-row GEMM + bf16 residual + fused norm, LDS-bounced coalesced epilogue.
// BM=128, BN=256=N, NY=1.  v = acc + bias + xres;
// MODE 0 (LayerNorm): xres<-bf16(v); lnout = sa*(v-mean)/(sqrt(var)+eps)+sb
// MODE 1 (BatchNorm): lnout = v*is*sa+sb only (xres not updated, dead).
// Epilogue: (1) xres->E coalesced u16x8; (2) fragment add+stats in LDS;
// (3) coalesced writeback xres<-E and lnout<-norm(E).
// ---------------------------------------------------------------------------
template <int MODE>
__global__ __launch_bounds__(512) void gemm8ln(
    const unsigned short* __restrict__ A, const unsigned short* __restrict__ W,
    const float* __restrict__ bias, unsigned short* __restrict__ xres,
    const float* __restrict__ sa, const float* __restrict__ sb,
    unsigned short* __restrict__ lnout, int K) {
  constexpr int ES = 264;                  // padded row stride (shorts)
  __shared__ unsigned short SM[128 * ES];  // union: K-loop A|B tiles / E
  __shared__ float redS[128][4];
  __shared__ float redQ[128][4];
  unsigned short* Alds = SM;
  unsigned short* Blds = SM + 128 * 64;

  const int tid = threadIdx.x, wave = tid >> 6, lane = tid & 63;
  const int nwg = gridDim.x;
  const int swz = (blockIdx.x & 7) * (nwg >> 3) + (blockIdx.x >> 3);
  const int row0 = swz * 128;
  const int wr = wave >> 2, wc = wave & 3;
  const int fr = lane & 15, g4 = lane >> 4, ko = g4 * 8;
  const int swr = (fr & 7) << 3;
  const int l8 = lane >> 3;
  const int lkS = ((lane & 7) ^ l8) * 8;

  f32x4 acc[4][4];
#pragma unroll
  for (int i = 0; i < 4; ++i)
#pragma unroll
    for (int j = 0; j < 4; ++j) acc[i][j] = (f32x4)0.f;

  const int nkt = K / 64;
  for (int kt = 0; kt < nkt; ++kt) {
    __syncthreads();
#pragma unroll
    for (int j = 0; j < 2; ++j) {
      int ci = wave * 2 + j;
      const unsigned short* src = A + (size_t)(row0 + ci * 8 + l8) * K + kt * 64 + lkS;
      GLD16(src, &Alds[ci * 512]);
    }
#pragma unroll
    for (int j = 0; j < 4; ++j) {
      int ci = wave * 4 + j;
      const unsigned short* src = W + (size_t)(ci * 8 + l8) * K + kt * 64 + lkS;
      GLD16(src, &Blds[ci * 512]);
    }
    __syncthreads();
#pragma unroll
    for (int kk = 0; kk < 2; ++kk) {
      s16x8 af[4], bfr[4];
#pragma unroll
      for (int i = 0; i < 4; ++i)
        af[i] = *(const s16x8*)&Alds[(wr * 64 + i * 16 + fr) * 64 + ((kk * 32 + ko) ^ swr)];
#pragma unroll
      for (int j = 0; j < 4; ++j)
        bfr[j] = *(const s16x8*)&Blds[(wc * 64 + j * 16 + fr) * 64 + ((kk * 32 + ko) ^ swr)];
#pragma unroll
      for (int i = 0; i < 4; ++i)
#pragma unroll
        for (int j = 0; j < 4; ++j)
          acc[i][j] =
              __builtin_amdgcn_mfma_f32_16x16x32_bf16(af[i], bfr[j], acc[i][j], 0, 0, 0);
    }
  }

  const int cr = g4 * 4;
  float bv[4];
#pragma unroll
  for (int j = 0; j < 4; ++j) bv[j] = bias[wc * 64 + j * 16 + fr];

  const int erow = tid >> 5;       // 0..15
  const int ec8 = (tid & 31) * 8;  // fixed 16B col chunk

  __syncthreads();  // all K-loop LDS reads done; SM is reusable as E
  // (1) coalesced xres -> E
#pragma unroll
  for (int p = 0; p < 8; ++p) {
    int row = p * 16 + erow;
    *(u16x8*)&SM[row * ES + ec8] =
        *(const u16x8*)&xres[(size_t)(row0 + row) * 256 + ec8];
  }
  __syncthreads();
  // (2) fragment add + stats in fp32; v back to E as bf16
#pragma unroll
  for (int i = 0; i < 4; ++i) {
    float s4[4] = {0.f, 0.f, 0.f, 0.f};
    float q4[4] = {0.f, 0.f, 0.f, 0.f};
#pragma unroll
    for (int j = 0; j < 4; ++j) {
      int col = wc * 64 + j * 16 + fr;
#pragma unroll
      for (int r = 0; r < 4; ++r) {
        int rl = wr * 64 + i * 16 + cr + r;
        float v = acc[i][j][r] + bv[j] + bf2f(SM[rl * ES + col]);
        SM[rl * ES + col] = f2bf(v);
        s4[r] += v;
        q4[r] += v * v;
      }
    }
    if constexpr (MODE == 0) {
#pragma unroll
      for (int r = 0; r < 4; ++r) {
        float s = s4[r], q = q4[r];
#pragma unroll
        for (int off = 1; off <= 8; off <<= 1) {
          s += __shfl_xor(s, off);
          q += __shfl_xor(q, off);
        }
        if (fr == 0) {
          int rl = wr * 64 + i * 16 + cr + r;
          redS[rl][wc] = s;
          redQ[rl][wc] = q;
        }
      }
    }
  }
  __syncthreads();
  // (3) coalesced writeback + norm
  f32x4 sa0 = *(const f32x4*)(sa + ec8), sa1 = *(const f32x4*)(sa + ec8 + 4);
  f32x4 sb0 = *(const f32x4*)(sb + ec8), sb1 = *(const f32x4*)(sb + ec8 + 4);
  if constexpr (MODE == 1) {
    const float is = 0.9999950000374997f;  // 1/sqrt(1+1e-5)
    sa0 *= is;
    sa1 *= is;
  }
#pragma unroll
  for (int p = 0; p < 8; ++p) {
    int row = p * 16 + erow;
    u16x8 vb = *(const u16x8*)&SM[row * ES + ec8];
    u16x8 o;
    if constexpr (MODE == 0) {
      *(u16x8*)&xres[(size_t)(row0 + row) * 256 + ec8] = vb;
      float s = redS[row][0] + redS[row][1] + redS[row][2] + redS[row][3];
      float q = redQ[row][0] + redQ[row][1] + redQ[row][2] + redQ[row][3];
      float mean = s * (1.f / 256.f);
      float var = fmaxf(q - 256.f * mean * mean, 0.f) * (1.f / 255.f);
      float scl = 1.f / (sqrtf(var) + 1e-6f);
#pragma unroll
      for (int e = 0; e < 4; ++e) {
        o[e] = f2bf(sa0[e] * (bf2f(vb[e]) - mean) * scl + sb0[e]);
        o[e + 4] = f2bf(sa1[e] * (bf2f(vb[e + 4]) - mean) * scl + sb1[e]);
      }
    } else {
#pragma unroll
      for (int e = 0; e < 4; ++e) {
        o[e] = f2bf(bf2f(vb[e]) * sa0[e] + sb0[e]);
        o[e + 4] = f2bf(bf2f(vb[e + 4]) * sa1[e] + sb1[e]);
      }
    }
    *(u16x8*)&lnout[(size_t)(row0 + row) * 256 + ec8] = o;
  }
}

// ---------------------------------------------------------------------------
// Final 51-col conv: BM=128, BN=64 (clamped rows), 4 waves 2x2, bf16 in.
// ---------------------------------------------------------------------------
__global__ __launch_bounds__(256) void gemm_cv(
    const unsigned short* __restrict__ A, const unsigned short* __restrict__ W,
    const float* __restrict__ bias, float* __restrict__ out) {
  constexpr int BM = 128, BK = 64, BN = 64, WN = 32, FN = 2;
  __shared__ unsigned short Alds[BM * BK];
  __shared__ unsigned short Blds[BN * BK];
  const int tid = threadIdx.x, wave = tid >> 6, lane = tid & 63;
  const int nwg = gridDim.x;
  const int swz = (blockIdx.x & 7) * (nwg >> 3) + (blockIdx.x >> 3);
  const int row0 = swz * BM;
  const int wr = wave >> 1, wc = wave & 1;
  const int fr = lane & 15, g4 = lane >> 4, ko = g4 * 8;
  const int swr = (fr & 7) << 3;
  const int l8 = lane >> 3;
  const int lkS = ((lane & 7) ^ l8) * 8;

  f32x4 acc[4][FN];
#pragma unroll
  for (int i = 0; i < 4; ++i)
#pragma unroll
    for (int j = 0; j < FN; ++j) acc[i][j] = (f32x4)0.f;

  for (int kt = 0; kt < 4; ++kt) {
    __syncthreads();
#pragma unroll
    for (int j = 0; j < 4; ++j) {
      int ci = wave * 4 + j;
      const unsigned short* src = A + (size_t)(row0 + ci * 8 + l8) * 256 + kt * BK + lkS;
      GLD16(src, &Alds[ci * 512]);
    }
    {
      int ci = wave * 2;
      int brow = ci * 8 + l8;
      if (brow > 50) brow = 50;
      const unsigned short* src = W + (size_t)brow * 256 + kt * BK + lkS;
      GLD16(src, &Blds[ci * 512]);
      int brow2 = (ci + 1) * 8 + l8;
      if (brow2 > 50) brow2 = 50;
      const unsigned short* src2 = W + (size_t)brow2 * 256 + kt * BK + lkS;
      GLD16(src2, &Blds[(ci + 1) * 512]);
    }
    __syncthreads();
#pragma unroll
    for (int kk = 0; kk < 2; ++kk) {
      s16x8 af[4], bfr[FN];
#pragma unroll
      for (int i = 0; i < 4; ++i)
        af[i] = *(const s16x8*)&Alds[(wr * 64 + i * 16 + fr) * BK + ((kk * 32 + ko) ^ swr)];
#pragma unroll
      for (int j = 0; j < FN; ++j)
        bfr[j] = *(const s16x8*)&Blds[(wc * WN + j * 16 + fr) * BK + ((kk * 32 + ko) ^ swr)];
#pragma unroll
      for (int i = 0; i < 4; ++i)
#pragma unroll
        for (int j = 0; j < FN; ++j)
          acc[i][j] =
              __builtin_amdgcn_mfma_f32_16x16x32_bf16(af[i], bfr[j], acc[i][j], 0, 0, 0);
    }
  }

  const int cr = g4 * 4;
#pragma unroll
  for (int i = 0; i < 4; ++i) {
#pragma unroll
    for (int j = 0; j < FN; ++j) {
      int col = wc * WN + j * 16 + fr;
      if (col >= 51) continue;
      float bv = bias[col];
#pragma unroll
      for (int r = 0; r < 4; ++r) {
        int row = row0 + wr * 64 + i * 16 + cr + r;
        out[(size_t)row * 51 + col] = acc[i][j][r] + bv;
      }
    }
  }
}

// ---------------------------------------------------------------------------
// Fused x+pos -> xres (bf16) and LayerNorm -> bufA (bf16). 1 wave per row.
// ---------------------------------------------------------------------------
__global__ __launch_bounds__(256) void addpos_ln(const f32x4* __restrict__ x,
                                                 const f32x4* __restrict__ pos,
                                                 const float* __restrict__ a,
                                                 const float* __restrict__ b,
                                                 unsigned short* __restrict__ xres,
                                                 unsigned short* __restrict__ lnout) {
  const int wave = threadIdx.x >> 6, lane = threadIdx.x & 63;
  const size_t row = (size_t)blockIdx.x * 4 + wave;
  f32x4 v = x[row * 64 + lane] + pos[(row % 81) * 64 + lane];
  u16x4 xb;
#pragma unroll
  for (int j = 0; j < 4; ++j) xb[j] = f2bf(v[j]);
  *(u16x4*)(xres + row * 256 + lane * 4) = xb;
  float s = v[0] + v[1] + v[2] + v[3];
#pragma unroll
  for (int off = 32; off >= 1; off >>= 1) s += __shfl_xor(s, off);
  float mean = s * (1.f / 256.f);
  f32x4 d = v - mean;
  float sq = d[0] * d[0] + d[1] * d[1] + d[2] * d[2] + d[3] * d[3];
#pragma unroll
  for (int off = 32; off >= 1; off >>= 1) sq += __shfl_xor(sq, off);
  float var = sq * (1.f / 255.f);
  float scl = 1.f / (sqrtf(var) + 1e-6f);
  f32x4 av = *(const f32x4*)(a + lane * 4);
  f32x4 bv = *(const f32x4*)(b + lane * 4);
  u16x4 ob;
#pragma unroll
  for (int j = 0; j < 4; ++j) ob[j] = f2bf(av[j] * d[j] * scl + bv[j]);
  *(u16x4*)(lnout + row * 256 + lane * 4) = ob;
}

// ---------------------------------------------------------------------------
// MFMA strided sparse attention. 1 wave = 1 stream (b,h,m); 4 waves/block.
// ---------------------------------------------------------------------------
__global__ __launch_bounds__(256) void attn_mfma(const unsigned short* __restrict__ qkv,
                                                 unsigned short* __restrict__ o) {
  constexpr int LS = 40;
  const int wave = threadIdx.x >> 6, lane = threadIdx.x & 63;
  const int sid = blockIdx.x * 4 + wave;
  const int m = sid % 3, hh = (sid / 3) & 7, b = sid / 24;
  __shared__ unsigned short VtS[4][32 * LS];
  __shared__ unsigned short PlS[4][32 * LS];
  unsigned short* vt = VtS[wave];
  unsigned short* pl = PlS[wave];

  const unsigned short* base = qkv + (size_t)b * 81 * 768 + (size_t)m * 768 + hh * 32;
  const int fr = lane & 15;
  const int ko = (lane >> 4) * 8;
  const int g4 = lane >> 4;

  s16x8 qf[2], kf[2];
#pragma unroll
  for (int i = 0; i < 2; ++i) {
    int g = fr + 16 * i;
    if (g > 26) g = 26;
    const unsigned short* qp = base + (size_t)g * 2304 + ko;
    qf[i] = *(const s16x8*)qp;
    kf[i] = *(const s16x8*)(qp + 256);
  }

#pragma unroll
  for (int it = 0; it < 2; ++it) {
    int slot = it * 64 + lane;
    int g = slot >> 2, s = slot & 3;
    if (g < 27) {
      u16x8 v = *(const u16x8*)(base + (size_t)g * 2304 + 512 + s * 8);
#pragma unroll
      for (int j = 0; j < 8; ++j) vt[(s * 8 + j) * LS + g] = v[j];
    } else {
#pragma unroll
      for (int j = 0; j < 8; ++j) vt[(s * 8 + j) * LS + g] = 0;
    }
  }

  f32x4 sacc[2][2];
#pragma unroll
  for (int i = 0; i < 2; ++i)
#pragma unroll
    for (int j = 0; j < 2; ++j) sacc[i][j] = (f32x4)0.f;
#pragma unroll
  for (int i = 0; i < 2; ++i)
#pragma unroll
    for (int j = 0; j < 2; ++j)
      sacc[i][j] = __builtin_amdgcn_mfma_f32_16x16x32_bf16(qf[i], kf[j], sacc[i][j], 0, 0, 0);

  const float scale = 0.17677669529663687f;
  const bool v1 = fr < 11;
#pragma unroll
  for (int i = 0; i < 2; ++i) {
#pragma unroll
    for (int r = 0; r < 4; ++r) {
      float a0 = sacc[i][0][r] * scale;
      float a1 = v1 ? sacc[i][1][r] * scale : -3.0e38f;
      float mx = fmaxf(a0, a1);
#pragma unroll
      for (int off = 1; off <= 8; off <<= 1) mx = fmaxf(mx, __shfl_xor(mx, off));
      float e0 = __expf(a0 - mx);
      float e1 = v1 ? __expf(a1 - mx) : 0.f;
      float sm = e0 + e1;
#pragma unroll
      for (int off = 1; off <= 8; off <<= 1) sm += __shfl_xor(sm, off);
      float inv = 1.f / sm;
      int row = i * 16 + 4 * g4 + r;
      pl[row * LS + fr] = f2bf(e0 * inv);
      pl[row * LS + 16 + fr] = f2bf(e1 * inv);
    }
  }
  __syncthreads();

  s16x8 pf[2], vf[2];
#pragma unroll
  for (int i = 0; i < 2; ++i) pf[i] = *(const s16x8*)&pl[(fr + 16 * i) * LS + ko];
#pragma unroll
  for (int j = 0; j < 2; ++j) vf[j] = *(const s16x8*)&vt[(fr + 16 * j) * LS + ko];

  f32x4 oacc[2][2];
#pragma unroll
  for (int i = 0; i < 2; ++i)
#pragma unroll
    for (int j = 0; j < 2; ++j) oacc[i][j] = (f32x4)0.f;
#pragma unroll
  for (int i = 0; i < 2; ++i)
#pragma unroll
    for (int j = 0; j < 2; ++j)
      oacc[i][j] = __builtin_amdgcn_mfma_f32_16x16x32_bf16(pf[i], vf[j], oacc[i][j], 0, 0, 0);

  __syncthreads();
#pragma unroll
  for (int i = 0; i < 2; ++i)
#pragma unroll
    for (int j = 0; j < 2; ++j)
#pragma unroll
      for (int r = 0; r < 4; ++r)
        vt[(i * 16 + 4 * g4 + r) * LS + j * 16 + fr] = f2bf(oacc[i][j][r]);
  __syncthreads();

#pragma unroll
  for (int it = 0; it < 2; ++it) {
    int slot = it * 64 + lane;
    int g = slot >> 2, s = slot & 3;
    if (g < 27) {
      u16x8 v = *(const u16x8*)&vt[g * LS + s * 8];
      *(u16x8*)(o + (size_t)(b * 81 + m + 3 * g) * 256 + hh * 32 + s * 8) = v;
    }
  }
}

__global__ __launch_bounds__(256) void cvt_kernel(const f32x4* __restrict__ src,
                                                  u16x4* __restrict__ dst, int n4) {
  int i = blockIdx.x * 256 + threadIdx.x;
  if (i < n4) {
    f32x4 v = src[i];
    u16x4 o;
#pragma unroll
    for (int j = 0; j < 4; ++j) o[j] = f2bf(v[j]);
    dst[i] = o;
  }
}

__global__ __launch_bounds__(256) void qkvpack_kernel(const float* __restrict__ Wq,
                                                      const float* __restrict__ Wk,
                                                      const float* __restrict__ Wv,
                                                      u16x4* __restrict__ dst) {
  int i4 = blockIdx.x * 256 + threadIdx.x;
  int e = i4 * 4;
  int l = e / 196608;
  int r = (e / 256) % 768;
  int c = e & 255;
  const float* src;
  if (r < 256) src = Wq + (size_t)l * 65536 + r * 256 + c;
  else if (r < 512) src = Wk + (size_t)l * 65536 + (r - 256) * 256 + c;
  else src = Wv + (size_t)l * 65536 + (r - 512) * 256 + c;
  f32x4 v = *(const f32x4*)src;
  u16x4 o;
#pragma unroll
  for (int j = 0; j < 4; ++j) o[j] = f2bf(v[j]);
  dst[i4] = o;
}

__global__ __launch_bounds__(256) void biaspack_kernel(const float* __restrict__ bq,
                                                       const float* __restrict__ bk,
                                                       const float* __restrict__ bv,
                                                       float* __restrict__ dst) {
  int i = blockIdx.x * 256 + threadIdx.x;
  if (i >= 2304) return;
  int l = i / 768, r = i % 768;
  float v = (r < 256) ? bq[l * 256 + r] : (r < 512) ? bk[l * 256 + r - 256]
                                                    : bv[l * 256 + r - 512];
  dst[i] = v;
}

extern "C" void kernel_launch(void* const* d_in, const int* in_sizes, int n_in,
                              void* d_out, int out_size, void* d_ws, size_t ws_size,
                              hipStream_t stream) {
  const float* x      = (const float*)d_in[0];
  const float* pos    = (const float*)d_in[1];
  const float* ln1_a  = (const float*)d_in[2];
  const float* ln1_b  = (const float*)d_in[3];
  const float* Wq     = (const float*)d_in[4];
  const float* bq     = (const float*)d_in[5];
  const float* Wk     = (const float*)d_in[6];
  const float* bk     = (const float*)d_in[7];
  const float* Wv     = (const float*)d_in[8];
  const float* bv     = (const float*)d_in[9];
  const float* Wo     = (const float*)d_in[10];
  const float* bo     = (const float*)d_in[11];
  const float* ln2_a  = (const float*)d_in[12];
  const float* ln2_b  = (const float*)d_in[13];
  const float* W1     = (const float*)d_in[14];
  const float* b1     = (const float*)d_in[15];
  const float* W2     = (const float*)d_in[16];
  const float* b2     = (const float*)d_in[17];
  const float* bn_g   = (const float*)d_in[18];
  const float* bn_b   = (const float*)d_in[19];
  const float* conv_w = (const float*)d_in[20];
  const float* conv_b = (const float*)d_in[21];

  char* ws = (char*)d_ws;
  unsigned short* xres = (unsigned short*)ws;  // bf16 residual stream
  unsigned short* bufA = (unsigned short*)(ws + 84934656);
  unsigned short* bufB = (unsigned short*)(ws + 127401984);
  unsigned short* wqkv3 = (unsigned short*)(ws + 254803968);
  unsigned short* wo3 = wqkv3 + 589824;
  unsigned short* w13 = wo3 + 196608;
  unsigned short* w23 = w13 + 393216;
  unsigned short* cw  = w23 + 393216;
  float* qkvb3 = (float*)(ws + 254803968 + 3171840);

  auto cvt = [&](const float* s, unsigned short* d, int n) {
    int n4 = n / 4;
    cvt_kernel<<<(n4 + 255) / 256, 256, 0, stream>>>((const f32x4*)s, (u16x4*)d, n4);
  };
  qkvpack_kernel<<<576, 256, 0, stream>>>(Wq, Wk, Wv, (u16x4*)wqkv3);
  biaspack_kernel<<<9, 256, 0, stream>>>(bq, bk, bv, qkvb3);
  cvt(Wo, wo3, 196608);
  cvt(W1, w13, 393216);
  cvt(W2, w23, 393216);
  cvt(conv_w, cw, 13056);

  addpos_ln<<<20736, 256, 0, stream>>>((const f32x4*)x, (const f32x4*)pos, ln1_a, ln1_b,
                                       xres, bufA);

  for (int l = 0; l < 3; ++l) {
    // fused QKV -> bufB [BT,768]
    gemm8<0, 3><<<1944, 512, 0, stream>>>(bufA, wqkv3 + l * 196608, qkvb3 + l * 768,
                                          (void*)bufB, 256, 768);
    attn_mfma<<<6144, 256, 0, stream>>>(bufB, bufA);
    // O-proj + resid(bf16) ; LN2 -> bufA
    gemm8ln<0><<<648, 512, 0, stream>>>(bufA, wo3 + l * 65536, bo + l * 256, xres,
                                        ln2_a + l * 256, ln2_b + l * 256, bufA, 256);
    // FFN1 (relu) -> bufB [BT,512]
    gemm8<1, 2><<<1296, 512, 0, stream>>>(bufA, w13 + l * 131072, b1 + l * 512,
                                          (void*)bufB, 256, 512);
    if (l < 2) {
      // FFN2 + resid(bf16) ; LN1(l+1) -> bufA
      gemm8ln<0><<<648, 512, 0, stream>>>(bufB, w23 + l * 131072, b2 + l * 256, xres,
                                          ln1_a + (l + 1) * 256, ln1_b + (l + 1) * 256,
                                          bufA, 512);
    } else {
      // FFN2 + resid ; BatchNorm -> bufA (xres not updated, dead)
      gemm8ln<1><<<648, 512, 0, stream>>>(bufB, w23 + l * 131072, b2 + l * 256, xres,
                                          bn_g, bn_b, bufA, 512);
    }
  }
  // final conv reads bf16 bufA -> d_out fp32
  gemm_cv<<<648, 256, 0, stream>>>(bufA, cw, conv_b, (float*)d_out);
}